// Round 4
// baseline (2432.355 us; speedup 1.0000x reference)
//
#include <hip/hip_runtime.h>

#define HID 2048
#define BAT 512
#define SEQ 128
#define NCLS 10

typedef __attribute__((ext_vector_type(4))) float f32x4;
typedef __attribute__((ext_vector_type(8))) short s16x8;
typedef __attribute__((ext_vector_type(4))) unsigned short u16x4;

__device__ __forceinline__ float bf2f(unsigned short u) {
  union { unsigned int i; float f; } v;
  v.i = ((unsigned int)u) << 16;
  return v.f;
}
__device__ __forceinline__ unsigned short f2bf(float f) {
  union { float f; unsigned int i; } v;
  v.f = f;
  unsigned int u = v.i;
  return (unsigned short)((u + 0x7fffu + ((u >> 16) & 1u)) >> 16);
}

// fp32 -> bf16, 4 elems/thread
__global__ __launch_bounds__(256) void cvt_kernel(const float* __restrict__ src,
                                                  unsigned short* __restrict__ dst,
                                                  int n) {
  int i = (blockIdx.x * 256 + threadIdx.x) * 4;
  if (i + 3 < n) {
    f32x4 v = *(const f32x4*)(src + i);
    u16x4 o;
    o.x = f2bf(v.x);
    o.y = f2bf(v.y);
    o.z = f2bf(v.z);
    o.w = f2bf(v.w);
    *(u16x4*)(dst + i) = o;
  }
}

// x[BAT][SEQ] -> xT[SEQ][BAT]
__global__ __launch_bounds__(256) void xpose_kernel(const float* __restrict__ x,
                                                    float* __restrict__ xT) {
  const int t = blockIdx.x;
  for (int b = threadIdx.x; b < BAT; b += 256)
    xT[t * BAT + b] = x[b * SEQ + t];
}

__device__ __forceinline__ void gload16(const void* g, void* l) {
  __builtin_amdgcn_global_load_lds(
      (const __attribute__((address_space(1))) unsigned int*)g,
      (__attribute__((address_space(3))) unsigned int*)l, 16, 0, 0);
}

// One step: hout[n][m] = tanh( sum_k W[m][k]*hin[n][k] + whx[m]*xT[t][n] + bh[m] )
// BM=BN=64, BK=64, 256 threads = 4 waves (2m x 2n); per-wave 32x32 = 2x2 frags
// of mfma 16x16x32 (LDS-read : MFMA balanced at 1.0 KB / MFMA).
// 3-buffer pipeline, counted s_waitcnt vmcnt(4) (T4) + raw s_barrier; lgkmcnt(0)
// before each barrier so ds_reads complete before the buffer is re-staged (WAR).
// T2 chunk-XOR swizzle (involution applied to global source + ds_read offset;
// LDS dest stays linear per global_load_lds contract).
__global__ __launch_bounds__(256) void step_kernel(
    const unsigned short* __restrict__ W,
    const unsigned short* __restrict__ hin,
    unsigned short* __restrict__ hout,
    const float* __restrict__ whx,   // [HID]
    const float* __restrict__ bh,    // [HID]
    const float* __restrict__ xT,    // [SEQ][BAT]
    int t) {
  __shared__ unsigned short ldsA[3][64 * 64];
  __shared__ unsigned short ldsB[3][64 * 64];

  const int tid = threadIdx.x;
  const int wave = tid >> 6;
  const int lane = tid & 63;
  const int m0 = blockIdx.x * 64;
  const int n0 = blockIdx.y * 64;
  const int wm = wave >> 1;   // 0..1
  const int wn = wave & 1;    // 0..1
  const int fl = lane & 15;
  const int hi = lane >> 4;   // 0..3

  // ---- staging: tile halves of 32 rows; thread covers linear dest byte tid*16
  const int r0 = tid >> 3;             // 0..31
  const int r1 = 32 + r0;
  const int c0 = (tid & 7) ^ (r0 & 7); // involution pre-swizzle of source chunk
  const int c1 = (tid & 7) ^ (r1 & 7);
  const unsigned short* gA0 = W + (size_t)(m0 + r0) * HID + c0 * 8;
  const unsigned short* gA1 = W + (size_t)(m0 + r1) * HID + c1 * 8;
  const unsigned short* gB0 = hin + (size_t)(n0 + r0) * HID + c0 * 8;
  const unsigned short* gB1 = hin + (size_t)(n0 + r1) * HID + c1 * 8;
  const int ldst = wave * 512;  // wave-uniform dest offset (shorts); lane*16B implicit

  // ---- fragment read offsets (swizzled): elem = row*64 + ((ch ^ (row&7))*8)
  int offA[2][2], offB[2][2];
#pragma unroll
  for (int f = 0; f < 2; ++f) {
#pragma unroll
    for (int ks = 0; ks < 2; ++ks) {
      const int ra = wm * 32 + f * 16 + fl;
      const int rb = wn * 32 + f * 16 + fl;
      const int ch = ks * 4 + hi;
      offA[f][ks] = ra * 64 + ((ch ^ (ra & 7)) * 8);
      offB[f][ks] = rb * 64 + ((ch ^ (rb & 7)) * 8);
    }
  }

  f32x4 acc[2][2] = {};

#define STAGE(kk, ab, bb)                    \
  do {                                       \
    gload16(gA0 + (kk), (ab) + ldst);        \
    gload16(gA1 + (kk), (ab) + 2048 + ldst); \
    gload16(gB0 + (kk), (bb) + ldst);        \
    gload16(gB1 + (kk), (bb) + 2048 + ldst); \
  } while (0)

#define COMPUTE(ab, bb)                                                                  \
  do {                                                                                   \
    _Pragma("unroll") for (int ks = 0; ks < 2; ++ks) {                                   \
      s16x8 a0 = *(const s16x8*)&(ab)[offA[0][ks]];                                      \
      s16x8 a1 = *(const s16x8*)&(ab)[offA[1][ks]];                                      \
      s16x8 b0 = *(const s16x8*)&(bb)[offB[0][ks]];                                      \
      s16x8 b1 = *(const s16x8*)&(bb)[offB[1][ks]];                                      \
      acc[0][0] = __builtin_amdgcn_mfma_f32_16x16x32_bf16(a0, b0, acc[0][0], 0, 0, 0);   \
      acc[0][1] = __builtin_amdgcn_mfma_f32_16x16x32_bf16(a0, b1, acc[0][1], 0, 0, 0);   \
      acc[1][0] = __builtin_amdgcn_mfma_f32_16x16x32_bf16(a1, b0, acc[1][0], 0, 0, 0);   \
      acc[1][1] = __builtin_amdgcn_mfma_f32_16x16x32_bf16(a1, b1, acc[1][1], 0, 0, 0);   \
    }                                                                                    \
  } while (0)

  unsigned short* aC = ldsA[0]; unsigned short* bC = ldsB[0];
  unsigned short* aN = ldsA[1]; unsigned short* bN = ldsB[1];
  unsigned short* aT = ldsA[2]; unsigned short* bT = ldsB[2];

  // prologue: tiles 0 and 1 in flight; wait tile 0 only (4 loads of tile 1 outstanding)
  STAGE(0, aC, bC);
  STAGE(64, aN, bN);
  asm volatile("s_waitcnt vmcnt(4)\n\ts_barrier" ::: "memory");

  // steady state: iters 0..29; tile ki+2 staged, tile ki computed, wait vmcnt(4)
  for (int ki = 0; ki < 30; ++ki) {
    STAGE((ki + 2) * 64, aT, bT);
    COMPUTE(aC, bC);
    asm volatile("s_waitcnt vmcnt(4) lgkmcnt(0)\n\ts_barrier" ::: "memory");
    unsigned short* ta = aC; aC = aN; aN = aT; aT = ta;
    unsigned short* tb = bC; bC = bN; bN = bT; bT = tb;
  }
  // epilogue: tiles 30, 31
  COMPUTE(aC, bC);
  asm volatile("s_waitcnt vmcnt(0) lgkmcnt(0)\n\ts_barrier" ::: "memory");
  COMPUTE(aN, bN);

#undef STAGE
#undef COMPUTE

  // ---- epilogue: C/D layout col(n)=lane&15, row(m)=hi*4+j  [m89/m91-verified]
  const int mbase = m0 + wm * 32;
  const int nbase = n0 + wn * 32;
#pragma unroll
  for (int mf = 0; mf < 2; ++mf) {
    const int mrow = mbase + mf * 16 + hi * 4;
    const f32x4 wx = *(const f32x4*)&whx[mrow];
    const f32x4 bv = *(const f32x4*)&bh[mrow];
#pragma unroll
    for (int nf = 0; nf < 2; ++nf) {
      const int ncol = nbase + nf * 16 + fl;
      const float xv = xT[t * BAT + ncol];
      u16x4 o;
#pragma unroll
      for (int j = 0; j < 4; ++j) {
        float z = acc[mf][nf][j] + wx[j] * xv + bv[j];
        o[j] = f2bf(tanhf(z));
      }
      *(u16x4*)&hout[(size_t)ncol * HID + mrow] = o;
    }
  }
}

// out[b][c] = sum_k wp[c][k] * hT[b][k] + bp[c]
__global__ __launch_bounds__(256) void proj_kernel(const unsigned short* __restrict__ hT,
                                                   const float* __restrict__ wp,
                                                   const float* __restrict__ bp,
                                                   float* __restrict__ out) {
  const int b = blockIdx.x;
  const int wave = threadIdx.x >> 6;
  const int lane = threadIdx.x & 63;
  for (int c = wave; c < NCLS; c += 4) {
    float s = 0.f;
    for (int k = lane * 8; k < HID; k += 512) {
      s16x8 hv = *(const s16x8*)&hT[b * HID + k];
      f32x4 w0 = *(const f32x4*)&wp[c * HID + k];
      f32x4 w1 = *(const f32x4*)&wp[c * HID + k + 4];
      s += w0.x * bf2f((unsigned short)hv[0]) + w0.y * bf2f((unsigned short)hv[1]) +
           w0.z * bf2f((unsigned short)hv[2]) + w0.w * bf2f((unsigned short)hv[3]) +
           w1.x * bf2f((unsigned short)hv[4]) + w1.y * bf2f((unsigned short)hv[5]) +
           w1.z * bf2f((unsigned short)hv[6]) + w1.w * bf2f((unsigned short)hv[7]);
    }
#pragma unroll
    for (int off = 32; off > 0; off >>= 1) s += __shfl_down(s, off);
    if (lane == 0) out[b * NCLS + c] = s + bp[c];
  }
}

extern "C" void kernel_launch(void* const* d_in, const int* in_sizes, int n_in,
                              void* d_out, int out_size, void* d_ws, size_t ws_size,
                              hipStream_t stream) {
  (void)in_sizes; (void)n_in; (void)out_size; (void)ws_size;
  const float* x   = (const float*)d_in[0];  // [BAT][SEQ]
  const float* whx = (const float*)d_in[1];  // [HID][1]
  const float* whh = (const float*)d_in[2];  // [HID][HID]
  const float* bh  = (const float*)d_in[3];  // [HID][1]
  const float* wp  = (const float*)d_in[4];  // [NCLS][HID]
  const float* bp  = (const float*)d_in[5];  // [NCLS][1]
  float* out = (float*)d_out;                // [BAT][NCLS]

  unsigned short* Wb = (unsigned short*)d_ws;          // 8 MiB
  unsigned short* h0 = Wb + (size_t)HID * HID;         // 2 MiB
  unsigned short* h1 = h0 + (size_t)BAT * HID;         // 2 MiB
  float* xT = (float*)(h1 + (size_t)BAT * HID);        // 256 KiB

  cvt_kernel<<<dim3((HID * HID) / 1024), 256, 0, stream>>>(whh, Wb, HID * HID);
  xpose_kernel<<<dim3(SEQ), 256, 0, stream>>>(x, xT);
  hipMemsetAsync(h0, 0, (size_t)BAT * HID * sizeof(unsigned short), stream);

  unsigned short* hin = h0;
  unsigned short* hout = h1;
  for (int t = 0; t < SEQ; ++t) {
    step_kernel<<<dim3(HID / 64, BAT / 64), 256, 0, stream>>>(Wb, hin, hout, whx, bh, xT, t);
    unsigned short* tmp = hin; hin = hout; hout = tmp;
  }
  // SEQ even -> final h in h0
  proj_kernel<<<dim3(BAT), 256, 0, stream>>>(hin, wp, bp, out);
}